// Round 2
// baseline (2159.896 us; speedup 1.0000x reference)
//
#include <hip/hip_runtime.h>
#include <math.h>

#define HEADS 4
#define CH 64
#define HC 256    // per-direction output channels
#define HID 512

__device__ __forceinline__ float lrelu(float x){ return x > 0.f ? x : 0.2f*x; }

// ---------- init ----------
__global__ void k_zero(int* cntD, int* cntS, float* gsum, float* gsq, int N){
  int i = blockIdx.x*blockDim.x + threadIdx.x;
  int stride = gridDim.x*blockDim.x;
  for(int j=i; j<N; j+=stride){ cntD[j]=0; cntS[j]=0; }
  if(i < HID){ gsum[i]=0.f; gsq[i]=0.f; }
}

// ---------- edge dtype detect / convert ----------
__global__ void k_detect(const int* __restrict__ ei32, int* flag){
  __shared__ int any;
  if(threadIdx.x==0) any = 0;
  __syncthreads();
  int v = 0;
  for(int i=threadIdx.x; i<1024; i+=blockDim.x) v |= ei32[2*i+1];
  if(v) atomicOr(&any, 1);
  __syncthreads();
  if(threadIdx.x==0) *flag = (any==0) ? 1 : 0;   // 1 => buffer is int64
}

__global__ void k_convert(const int* __restrict__ ei32, const int* __restrict__ flag,
                          int* __restrict__ src, int* __restrict__ dst, int E){
  int i = blockIdx.x*blockDim.x + threadIdx.x;
  if(i>=E) return;
  if(*flag){ src[i] = ei32[2*i];  dst[i] = ei32[2*(E+i)]; }
  else     { src[i] = ei32[i];    dst[i] = ei32[E+i];     }
}

// ---------- f32 tiled GEMM: C[M,Nc] = A[M,K] @ B[K,Nc] (+bias) ----------
__global__ __launch_bounds__(256) void k_gemm_f32(
    const float* __restrict__ A, const float* __restrict__ B,
    float* __restrict__ C, int M, int Nc, int K, const float* __restrict__ bias){
  __shared__ float As[16][65];
  __shared__ float Bs[16][65];
  int tid = threadIdx.x;
  int tx = tid & 15, ty = tid >> 4;
  int row0 = blockIdx.y * 64, col0 = blockIdx.x * 64;
  float acc[4][4] = {};
  for(int kt=0; kt<K; kt+=16){
    #pragma unroll
    for(int i=0;i<4;i++){
      int idx = tid + i*256;          // 0..1023
      int r = idx >> 4, kk = idx & 15;
      int gr = row0 + r;
      As[kk][r] = (gr < M) ? A[(long)gr*K + kt + kk] : 0.f;
    }
    #pragma unroll
    for(int i=0;i<4;i++){
      int idx = tid + i*256;
      int kk = idx >> 6, c = idx & 63;
      Bs[kk][c] = B[(long)(kt+kk)*Nc + col0 + c];
    }
    __syncthreads();
    #pragma unroll
    for(int kk=0; kk<16; kk++){
      float a[4], b[4];
      #pragma unroll
      for(int i=0;i<4;i++) a[i] = As[kk][ty*4+i];
      #pragma unroll
      for(int j=0;j<4;j++) b[j] = Bs[kk][tx*4+j];
      #pragma unroll
      for(int i=0;i<4;i++)
        #pragma unroll
        for(int j=0;j<4;j++) acc[i][j] += a[i]*b[j];
    }
    __syncthreads();
  }
  #pragma unroll
  for(int i=0;i<4;i++){
    int gr = row0 + ty*4 + i;
    if(gr >= M) continue;
    #pragma unroll
    for(int j=0;j<4;j++){
      int gc = col0 + tx*4 + j;
      float v = acc[i][j];
      if(bias) v += bias[gc];
      C[(long)gr*Nc + gc] = v;
    }
  }
}

// ---------- per-node attention dots: a_s/a_d for both directions ----------
__global__ __launch_bounds__(256) void k_att(
    const float* __restrict__ hf, const float* __restrict__ hb,
    const float* __restrict__ att_sf, const float* __restrict__ att_df,
    const float* __restrict__ att_sb, const float* __restrict__ att_db,
    float4* __restrict__ asf, float4* __restrict__ adf,
    float4* __restrict__ asb, float4* __restrict__ adb, int N){
  int w = (blockIdx.x*(blockDim.x>>6)) + (threadIdx.x>>6);
  int lane = threadIdx.x & 63;
  if(w >= N) return;
  float psf[4], pdf_[4], psb[4], pdb_[4];
  #pragma unroll
  for(int i=0;i<4;i++){
    float vf = hf[(long)w*HC + i*64 + lane];
    float vb = hb[(long)w*HC + i*64 + lane];
    psf[i]  = vf*att_sf[i*64+lane];  pdf_[i] = vf*att_df[i*64+lane];
    psb[i]  = vb*att_sb[i*64+lane];  pdb_[i] = vb*att_db[i*64+lane];
  }
  #pragma unroll
  for(int off=32; off; off>>=1){
    #pragma unroll
    for(int i=0;i<4;i++){
      psf[i]  += __shfl_xor(psf[i],  off);
      pdf_[i] += __shfl_xor(pdf_[i], off);
      psb[i]  += __shfl_xor(psb[i],  off);
      pdb_[i] += __shfl_xor(pdb_[i], off);
    }
  }
  if(lane==0){
    asf[w] = make_float4(psf[0],psf[1],psf[2],psf[3]);
    adf[w] = make_float4(pdf_[0],pdf_[1],pdf_[2],pdf_[3]);
    asb[w] = make_float4(psb[0],psb[1],psb[2],psb[3]);
    adb[w] = make_float4(pdb_[0],pdb_[1],pdb_[2],pdb_[3]);
  }
}

// ---------- per-edge logits + degree counts ----------
__global__ void k_edge(const int* __restrict__ src, const int* __restrict__ dst,
    const float4* __restrict__ asf, const float4* __restrict__ adf,
    const float4* __restrict__ asb, const float4* __restrict__ adb,
    float4* __restrict__ ef, float4* __restrict__ eb,
    int* __restrict__ cntD, int* __restrict__ cntS, int E){
  int e = blockIdx.x*blockDim.x + threadIdx.x;
  if(e>=E) return;
  int s = src[e], d = dst[e];
  float4 a = asf[s], b = adf[d], r;
  r.x = lrelu(a.x+b.x); r.y = lrelu(a.y+b.y); r.z = lrelu(a.z+b.z); r.w = lrelu(a.w+b.w);
  ef[e] = r;
  a = asb[d]; b = adb[s];
  r.x = lrelu(a.x+b.x); r.y = lrelu(a.y+b.y); r.z = lrelu(a.z+b.z); r.w = lrelu(a.w+b.w);
  eb[e] = r;
  atomicAdd(&cntD[d], 1);
  atomicAdd(&cntS[s], 1);
}

// ---------- single-block scan: cnt[n] -> row_start[n+1], cursor copy ----------
__global__ __launch_bounds__(1024) void k_scan(const int* __restrict__ cnt, int n,
                                               int* __restrict__ rs, int* __restrict__ cur){
  __shared__ int sh[1024];
  __shared__ int carry;
  int tid = threadIdx.x;
  if(tid==0) carry = 0;
  __syncthreads();
  for(int base=0; base<n; base+=1024){
    int i = base + tid;
    int v = (i<n) ? cnt[i] : 0;
    sh[tid] = v;
    __syncthreads();
    for(int off=1; off<1024; off<<=1){
      int t = (tid>=off) ? sh[tid-off] : 0;
      __syncthreads();
      sh[tid] += t;
      __syncthreads();
    }
    int incl = sh[tid];
    if(i<n){ int e0 = carry + incl - v; rs[i] = e0; cur[i] = e0; }
    __syncthreads();
    if(tid==0) carry += sh[1023];
    __syncthreads();
  }
  if(tid==0) rs[n] = carry;
}

// ---------- scatter edges into CSR order ----------
__global__ void k_scatter(const int* __restrict__ src, const int* __restrict__ dst,
    int* __restrict__ curD, int* __restrict__ curS,
    int* __restrict__ listD, int* __restrict__ listS, int E){
  int e = blockIdx.x*blockDim.x + threadIdx.x;
  if(e>=E) return;
  int p = atomicAdd(&curD[dst[e]], 1);  listD[p] = e;
  int q = atomicAdd(&curS[src[e]], 1);  listS[q] = e;
}

// ---------- per-node softmax + weighted aggregation (one wave / node) ----------
__global__ __launch_bounds__(256) void k_agg(
    const int* __restrict__ rs, const int* __restrict__ list,
    const float4* __restrict__ etab, const int* __restrict__ gidx,
    const float* __restrict__ htab, const float* __restrict__ bias,
    float* __restrict__ combined, int N, int out_off){
  int w = (blockIdx.x*(blockDim.x>>6)) + (threadIdx.x>>6);
  int lane = threadIdx.x & 63;
  if(w >= N) return;
  int beg = rs[w], end = rs[w+1];
  float4 m = make_float4(-1e30f,-1e30f,-1e30f,-1e30f);
  for(int j=beg+lane; j<end; j+=64){
    float4 ev = etab[list[j]];
    m.x = fmaxf(m.x, ev.x); m.y = fmaxf(m.y, ev.y);
    m.z = fmaxf(m.z, ev.z); m.w = fmaxf(m.w, ev.w);
  }
  #pragma unroll
  for(int off=32; off; off>>=1){
    m.x = fmaxf(m.x, __shfl_xor(m.x, off));
    m.y = fmaxf(m.y, __shfl_xor(m.y, off));
    m.z = fmaxf(m.z, __shfl_xor(m.z, off));
    m.w = fmaxf(m.w, __shfl_xor(m.w, off));
  }
  float4 acc = make_float4(0,0,0,0);
  float4 den = make_float4(0,0,0,0);
  for(int j=beg; j<end; j++){
    int e = list[j];
    float4 ev = etab[e];
    int g = gidx[e];
    const float* hp = htab + (long)g*HC;
    float e0 = __expf(ev.x - m.x), e1 = __expf(ev.y - m.y);
    float e2 = __expf(ev.z - m.z), e3 = __expf(ev.w - m.w);
    den.x += e0; den.y += e1; den.z += e2; den.w += e3;
    acc.x += e0 * hp[lane];
    acc.y += e1 * hp[64+lane];
    acc.z += e2 * hp[128+lane];
    acc.w += e3 * hp[192+lane];
  }
  float* co = combined + (long)w*HID + out_off;
  co[lane]       = acc.x/(den.x+1e-16f) + bias[lane];
  co[64+lane]    = acc.y/(den.y+1e-16f) + bias[64+lane];
  co[128+lane]   = acc.z/(den.z+1e-16f) + bias[128+lane];
  co[192+lane]   = acc.w/(den.w+1e-16f) + bias[192+lane];
}

// ---------- batchnorm ----------
__global__ __launch_bounds__(512) void k_bn_stats(const float* __restrict__ fused, int N,
                                                  float* __restrict__ gsum, float* __restrict__ gsq){
  int c = threadIdx.x;
  int rows_per = (N + gridDim.x - 1) / gridDim.x;
  int r0 = blockIdx.x * rows_per;
  int r1 = min(N, r0 + rows_per);
  float s = 0.f, q = 0.f;
  for(int r=r0; r<r1; r++){
    float v = fused[(long)r*HID + c];
    s += v; q += v*v;
  }
  atomicAdd(&gsum[c], s);
  atomicAdd(&gsq[c], q);
}

__global__ __launch_bounds__(512) void k_bn_final(const float* __restrict__ gsum, const float* __restrict__ gsq,
    const float* __restrict__ gamma, const float* __restrict__ beta,
    float* __restrict__ scale, float* __restrict__ shift, int N){
  int c = threadIdx.x;
  float mean = gsum[c] / (float)N;
  float var  = gsq[c] / (float)N - mean*mean;
  float sc = gamma[c] * rsqrtf(var + 1e-5f);
  scale[c] = sc;
  shift[c] = beta[c] - mean*sc;
}

__global__ void k_bn_apply(const float4* __restrict__ fused4, const float4* __restrict__ scale4,
                           const float4* __restrict__ shift4, float4* __restrict__ out4, long n4){
  long i = (long)blockIdx.x*blockDim.x + threadIdx.x;
  long stride = (long)gridDim.x*blockDim.x;
  for(long j=i; j<n4; j+=stride){
    float4 v = fused4[j];
    int c4 = (int)(j & 127);
    float4 sc = scale4[c4], sh = shift4[c4];
    float4 r;
    r.x = fmaxf(v.x*sc.x + sh.x, 0.f);
    r.y = fmaxf(v.y*sc.y + sh.y, 0.f);
    r.z = fmaxf(v.z*sc.z + sh.z, 0.f);
    r.w = fmaxf(v.w*sc.w + sh.w, 0.f);
    out4[j] = r;
  }
}

// ---------- host ----------
extern "C" void kernel_launch(void* const* d_in, const int* in_sizes, int n_in,
                              void* d_out, int out_size, void* d_ws, size_t ws_size,
                              hipStream_t stream){
  const float* x        = (const float*)d_in[0];
  const int*   ei32     = (const int*)  d_in[1];
  const float* W_f      = (const float*)d_in[2];
  const float* att_sf   = (const float*)d_in[3];
  const float* att_df   = (const float*)d_in[4];
  const float* bias_f   = (const float*)d_in[5];
  const float* W_b      = (const float*)d_in[6];
  const float* att_sb   = (const float*)d_in[7];
  const float* att_db   = (const float*)d_in[8];
  const float* bias_b   = (const float*)d_in[9];
  const float* W_fuse   = (const float*)d_in[10];
  const float* b_fuse   = (const float*)d_in[11];
  const float* bn_gamma = (const float*)d_in[12];
  const float* bn_beta  = (const float*)d_in[13];

  const int N = in_sizes[0] / 512;
  const int E = in_sizes[1] / 2;

  char* ws = (char*)d_ws;
  size_t off = 0;
  auto alloc = [&](size_t bytes)->char*{
    char* p = ws + off;
    off = (off + bytes + 255) & ~(size_t)255;
    return p;
  };

  int*   srcI   = (int*)  alloc((size_t)E*4);
  int*   dstI   = (int*)  alloc((size_t)E*4);
  float* hbuf   = (float*)alloc((size_t)N*HID*4);   // h_f | h_b ; later aliased as `fused`
  float* h_f    = hbuf;
  float* h_b    = hbuf + (size_t)N*HC;
  float4* asf   = (float4*)alloc((size_t)N*16);
  float4* adf   = (float4*)alloc((size_t)N*16);
  float4* asb   = (float4*)alloc((size_t)N*16);
  float4* adb   = (float4*)alloc((size_t)N*16);
  float4* e_f   = (float4*)alloc((size_t)E*16);
  float4* e_b   = (float4*)alloc((size_t)E*16);
  int*   rsD    = (int*)  alloc((size_t)(N+1)*4);
  int*   curD   = (int*)  alloc((size_t)N*4);
  int*   listD  = (int*)  alloc((size_t)E*4);
  int*   rsS    = (int*)  alloc((size_t)(N+1)*4);
  int*   curS   = (int*)  alloc((size_t)N*4);
  int*   listS  = (int*)  alloc((size_t)E*4);
  float* combined = (float*)alloc((size_t)N*HID*4);
  float* gsum   = (float*)alloc(HID*4);
  float* gsq    = (float*)alloc(HID*4);
  float* scale  = (float*)alloc(HID*4);
  float* shift  = (float*)alloc(HID*4);
  int*   flag   = (int*)  alloc(4);
  float* fused  = hbuf;  // alias: h_f/h_b dead after aggregation

  // counts / stat accumulators must be zeroed every call (ws is poisoned)
  k_zero<<<256, 256, 0, stream>>>( (int*)curD, (int*)curS, gsum, gsq, N); // cur used as cnt first
  k_detect<<<1, 256, 0, stream>>>(ei32, flag);
  k_convert<<<(E+255)/256, 256, 0, stream>>>(ei32, flag, srcI, dstI, E);

  // h = x @ W  (both directions)
  k_gemm_f32<<<dim3(HC/64, (N+63)/64), 256, 0, stream>>>(x, W_f, h_f, N, HC, 512, nullptr);
  k_gemm_f32<<<dim3(HC/64, (N+63)/64), 256, 0, stream>>>(x, W_b, h_b, N, HC, 512, nullptr);

  int nodeBlocks = (N + 3) / 4;   // 4 waves per 256-thread block
  k_att<<<nodeBlocks, 256, 0, stream>>>(h_f, h_b, att_sf, att_df, att_sb, att_db,
                                        asf, adf, asb, adb, N);

  k_edge<<<(E+255)/256, 256, 0, stream>>>(srcI, dstI, asf, adf, asb, adb,
                                          e_f, e_b, curD, curS, E);

  k_scan<<<1, 1024, 0, stream>>>(curD, N, rsD, curD);
  k_scan<<<1, 1024, 0, stream>>>(curS, N, rsS, curS);

  k_scatter<<<(E+255)/256, 256, 0, stream>>>(srcI, dstI, curD, curS, listD, listS, E);

  // fwd: segments by dst, gather h_f[src];  bwd: segments by src, gather h_b[dst]
  k_agg<<<nodeBlocks, 256, 0, stream>>>(rsD, listD, e_f, srcI, h_f, bias_f, combined, N, 0);
  k_agg<<<nodeBlocks, 256, 0, stream>>>(rsS, listS, e_b, dstI, h_b, bias_b, combined, N, HC);

  // fused = combined @ W_fuse + b_fuse   (writes over dead h region)
  k_gemm_f32<<<dim3(HID/64, (N+63)/64), 256, 0, stream>>>(combined, W_fuse, fused, N, HID, 512, b_fuse);

  k_bn_stats<<<128, 512, 0, stream>>>(fused, N, gsum, gsq);
  k_bn_final<<<1, 512, 0, stream>>>(gsum, gsq, bn_gamma, bn_beta, scale, shift, N);
  long n4 = (long)N * HID / 4;
  k_bn_apply<<<2048, 256, 0, stream>>>((const float4*)fused, (const float4*)scale,
                                       (const float4*)shift, (float4*)d_out, n4);

  (void)n_in; (void)out_size; (void)ws_size;
}

// Round 3
// 1247.980 us; speedup vs baseline: 1.7307x; 1.7307x over previous
//
#include <hip/hip_runtime.h>
#include <math.h>

#define HEADS 4
#define CH 64
#define HC 256    // per-direction output channels
#define HID 512
#define KDIM 512

typedef __attribute__((ext_vector_type(8))) short short8;
typedef __attribute__((ext_vector_type(4))) float f32x4;
typedef __attribute__((ext_vector_type(4))) unsigned short us4;

__device__ __forceinline__ float lrelu(float x){ return x > 0.f ? x : 0.2f*x; }

__device__ __forceinline__ unsigned short f2bf(float f){
  unsigned u = __float_as_uint(f);
  unsigned r = (u + 0x7FFFu + ((u >> 16) & 1u)) >> 16;
  return (unsigned short)r;
}

// ---------- init ----------
__global__ void k_zero(int* cntD, int* cntS, float* gsum, float* gsq, int N){
  int i = blockIdx.x*blockDim.x + threadIdx.x;
  int stride = gridDim.x*blockDim.x;
  for(int j=i; j<N; j+=stride){ cntD[j]=0; cntS[j]=0; }
  if(i < HID){ gsum[i]=0.f; gsq[i]=0.f; }
}

// ---------- edge dtype detect / convert ----------
__global__ void k_detect(const int* __restrict__ ei32, int* flag){
  __shared__ int any;
  if(threadIdx.x==0) any = 0;
  __syncthreads();
  int v = 0;
  for(int i=threadIdx.x; i<1024; i+=blockDim.x) v |= ei32[2*i+1];
  if(v) atomicOr(&any, 1);
  __syncthreads();
  if(threadIdx.x==0) *flag = (any==0) ? 1 : 0;   // 1 => buffer is int64
}

__global__ void k_convert(const int* __restrict__ ei32, const int* __restrict__ flag,
                          int* __restrict__ src, int* __restrict__ dst, int E){
  int i = blockIdx.x*blockDim.x + threadIdx.x;
  if(i>=E) return;
  if(*flag){ src[i] = ei32[2*i];  dst[i] = ei32[2*(E+i)]; }
  else     { src[i] = ei32[i];    dst[i] = ei32[E+i];     }
}

// ---------- f32 -> bf16 row-copy (x) ----------
__global__ void k_cvt_x(const float4* __restrict__ in4, uint2* __restrict__ out2, long n4){
  long i = (long)blockIdx.x*blockDim.x + threadIdx.x;
  long stride = (long)gridDim.x*blockDim.x;
  for(long j=i; j<n4; j+=stride){
    float4 v = in4[j];
    uint2 o;
    o.x = (unsigned)f2bf(v.x) | ((unsigned)f2bf(v.y) << 16);
    o.y = (unsigned)f2bf(v.z) | ((unsigned)f2bf(v.w) << 16);
    out2[j] = o;
  }
}

// ---------- transpose+convert weights: dst[n][k] = src[k][n], bf16 ----------
__global__ void k_transcvt(const float* __restrict__ src, unsigned short* __restrict__ dst,
                           int K, int C){
  int i = blockIdx.x*blockDim.x + threadIdx.x;
  if(i >= C*K) return;
  int n = i / K;
  int k = i - n*K;
  dst[(size_t)n*K + k] = f2bf(src[(size_t)k*C + n]);
}

// ---------- bf16 MFMA GEMM: C[M,Nc] = A[Mp,K](bf16) @ Bt[Nc,K]^T (+bias) ----------
// 128x128 tile, 4 waves, each wave 64x64 (4x4 frags of 16x16x32), BK=32, reg-staged LDS.
__global__ __launch_bounds__(256) void k_gemm_mfma(
    const unsigned short* __restrict__ A,   // [Mp][K] bf16 row-major (padded rows ok)
    const unsigned short* __restrict__ Bt,  // [Nc][K] bf16 row-major
    float* __restrict__ C, int M, int Nc, int K, const float* __restrict__ bias){
  __shared__ __align__(16) unsigned short Asm[128*32];
  __shared__ __align__(16) unsigned short Bsm[128*32];
  int tid = threadIdx.x;
  int w = tid >> 6, lane = tid & 63;
  int wr = (w >> 1) * 64, wc = (w & 1) * 64;
  int lcol = lane & 15, lkb = lane >> 4;       // fragment row/col and k-block
  int row0 = blockIdx.y * 128, col0 = blockIdx.x * 128;

  // staging decomposition: chunk c in 0..511 per tile, 8 bf16 per chunk
  int c0 = tid, c1 = tid + 256;
  int ar0 = c0 >> 2, ak0 = (c0 & 3) * 8;
  int ar1 = c1 >> 2, ak1 = (c1 & 3) * 8;

  f32x4 acc[4][4] = {};

  for(int kt = 0; kt < K; kt += 32){
    // load 16B per thread per operand-half
    short8 va0 = *(const short8*)(A  + (size_t)(row0 + ar0)*K + kt + ak0);
    short8 va1 = *(const short8*)(A  + (size_t)(row0 + ar1)*K + kt + ak1);
    short8 vb0 = *(const short8*)(Bt + (size_t)(col0 + ar0)*K + kt + ak0);
    short8 vb1 = *(const short8*)(Bt + (size_t)(col0 + ar1)*K + kt + ak1);
    __syncthreads();   // previous tile's reads complete before overwrite
    *(short8*)(Asm + ar0*32 + ak0) = va0;
    *(short8*)(Asm + ar1*32 + ak1) = va1;
    *(short8*)(Bsm + ar0*32 + ak0) = vb0;
    *(short8*)(Bsm + ar1*32 + ak1) = vb1;
    __syncthreads();

    short8 af[4], bf[4];
    #pragma unroll
    for(int mi=0; mi<4; mi++)
      af[mi] = *(const short8*)(Asm + (wr + mi*16 + lcol)*32 + lkb*8);
    #pragma unroll
    for(int ni=0; ni<4; ni++)
      bf[ni] = *(const short8*)(Bsm + (wc + ni*16 + lcol)*32 + lkb*8);
    #pragma unroll
    for(int mi=0; mi<4; mi++)
      #pragma unroll
      for(int ni=0; ni<4; ni++)
        acc[mi][ni] = __builtin_amdgcn_mfma_f32_16x16x32_bf16(af[mi], bf[ni], acc[mi][ni], 0, 0, 0);
  }

  int lr = (lane >> 4) * 4;
  #pragma unroll
  for(int mi=0; mi<4; mi++){
    int gr0 = row0 + wr + mi*16 + lr;
    #pragma unroll
    for(int ni=0; ni<4; ni++){
      int gc = col0 + wc + ni*16 + lcol;
      float bv = bias ? bias[gc] : 0.f;
      #pragma unroll
      for(int r=0; r<4; r++){
        int gr = gr0 + r;
        if(gr < M) C[(size_t)gr*Nc + gc] = acc[mi][ni][r] + bv;
      }
    }
  }
}

// ---------- per-node attention dots (h is [N][512]: fwd cols 0..255, bwd 256..511) ----------
__global__ __launch_bounds__(256) void k_att(
    const float* __restrict__ h,
    const float* __restrict__ att_sf, const float* __restrict__ att_df,
    const float* __restrict__ att_sb, const float* __restrict__ att_db,
    float4* __restrict__ asf, float4* __restrict__ adf,
    float4* __restrict__ asb, float4* __restrict__ adb, int N){
  int w = (blockIdx.x*(blockDim.x>>6)) + (threadIdx.x>>6);
  int lane = threadIdx.x & 63;
  if(w >= N) return;
  float psf[4], pdf_[4], psb[4], pdb_[4];
  #pragma unroll
  for(int i=0;i<4;i++){
    float vf = h[(size_t)w*HID + i*64 + lane];
    float vb = h[(size_t)w*HID + 256 + i*64 + lane];
    psf[i]  = vf*att_sf[i*64+lane];  pdf_[i] = vf*att_df[i*64+lane];
    psb[i]  = vb*att_sb[i*64+lane];  pdb_[i] = vb*att_db[i*64+lane];
  }
  #pragma unroll
  for(int off=32; off; off>>=1){
    #pragma unroll
    for(int i=0;i<4;i++){
      psf[i]  += __shfl_xor(psf[i],  off);
      pdf_[i] += __shfl_xor(pdf_[i], off);
      psb[i]  += __shfl_xor(psb[i],  off);
      pdb_[i] += __shfl_xor(pdb_[i], off);
    }
  }
  if(lane==0){
    asf[w] = make_float4(psf[0],psf[1],psf[2],psf[3]);
    adf[w] = make_float4(pdf_[0],pdf_[1],pdf_[2],pdf_[3]);
    asb[w] = make_float4(psb[0],psb[1],psb[2],psb[3]);
    adb[w] = make_float4(pdb_[0],pdb_[1],pdb_[2],pdb_[3]);
  }
}

// ---------- per-edge logits + degree counts ----------
__global__ void k_edge(const int* __restrict__ src, const int* __restrict__ dst,
    const float4* __restrict__ asf, const float4* __restrict__ adf,
    const float4* __restrict__ asb, const float4* __restrict__ adb,
    float4* __restrict__ ef, float4* __restrict__ eb,
    int* __restrict__ cntD, int* __restrict__ cntS, int E){
  int e = blockIdx.x*blockDim.x + threadIdx.x;
  if(e>=E) return;
  int s = src[e], d = dst[e];
  float4 a = asf[s], b = adf[d], r;
  r.x = lrelu(a.x+b.x); r.y = lrelu(a.y+b.y); r.z = lrelu(a.z+b.z); r.w = lrelu(a.w+b.w);
  ef[e] = r;
  a = asb[d]; b = adb[s];
  r.x = lrelu(a.x+b.x); r.y = lrelu(a.y+b.y); r.z = lrelu(a.z+b.z); r.w = lrelu(a.w+b.w);
  eb[e] = r;
  atomicAdd(&cntD[d], 1);
  atomicAdd(&cntS[s], 1);
}

// ---------- single-block scan: cnt[n] -> row_start[n+1], cursor copy ----------
__global__ __launch_bounds__(1024) void k_scan(const int* __restrict__ cnt, int n,
                                               int* __restrict__ rs, int* __restrict__ cur){
  __shared__ int sh[1024];
  __shared__ int carry;
  int tid = threadIdx.x;
  if(tid==0) carry = 0;
  __syncthreads();
  for(int base=0; base<n; base+=1024){
    int i = base + tid;
    int v = (i<n) ? cnt[i] : 0;
    sh[tid] = v;
    __syncthreads();
    for(int off=1; off<1024; off<<=1){
      int t = (tid>=off) ? sh[tid-off] : 0;
      __syncthreads();
      sh[tid] += t;
      __syncthreads();
    }
    int incl = sh[tid];
    if(i<n){ int e0 = carry + incl - v; rs[i] = e0; cur[i] = e0; }
    __syncthreads();
    if(tid==0) carry += sh[1023];
    __syncthreads();
  }
  if(tid==0) rs[n] = carry;
}

// ---------- scatter edges into CSR order ----------
__global__ void k_scatter(const int* __restrict__ src, const int* __restrict__ dst,
    int* __restrict__ curD, int* __restrict__ curS,
    int* __restrict__ listD, int* __restrict__ listS, int E){
  int e = blockIdx.x*blockDim.x + threadIdx.x;
  if(e>=E) return;
  int p = atomicAdd(&curD[dst[e]], 1);  listD[p] = e;
  int q = atomicAdd(&curS[src[e]], 1);  listS[q] = e;
}

// ---------- per-node softmax + weighted aggregation; writes bf16 combined ----------
__global__ __launch_bounds__(256) void k_agg(
    const int* __restrict__ rs, const int* __restrict__ list,
    const float4* __restrict__ etab, const int* __restrict__ gidx,
    const float* __restrict__ h, int hoff, const float* __restrict__ bias,
    unsigned short* __restrict__ combined, int N, int out_off){
  int w = (blockIdx.x*(blockDim.x>>6)) + (threadIdx.x>>6);
  int lane = threadIdx.x & 63;
  if(w >= N) return;
  int beg = rs[w], end = rs[w+1];
  float4 m = make_float4(-1e30f,-1e30f,-1e30f,-1e30f);
  for(int j=beg+lane; j<end; j+=64){
    float4 ev = etab[list[j]];
    m.x = fmaxf(m.x, ev.x); m.y = fmaxf(m.y, ev.y);
    m.z = fmaxf(m.z, ev.z); m.w = fmaxf(m.w, ev.w);
  }
  #pragma unroll
  for(int off=32; off; off>>=1){
    m.x = fmaxf(m.x, __shfl_xor(m.x, off));
    m.y = fmaxf(m.y, __shfl_xor(m.y, off));
    m.z = fmaxf(m.z, __shfl_xor(m.z, off));
    m.w = fmaxf(m.w, __shfl_xor(m.w, off));
  }
  float4 acc = make_float4(0,0,0,0);
  float4 den = make_float4(0,0,0,0);
  for(int j=beg; j<end; j++){
    int e = list[j];
    float4 ev = etab[e];
    int g = gidx[e];
    const float* hp = h + (size_t)g*HID + hoff;
    float e0 = __expf(ev.x - m.x), e1 = __expf(ev.y - m.y);
    float e2 = __expf(ev.z - m.z), e3 = __expf(ev.w - m.w);
    den.x += e0; den.y += e1; den.z += e2; den.w += e3;
    acc.x += e0 * hp[lane];
    acc.y += e1 * hp[64+lane];
    acc.z += e2 * hp[128+lane];
    acc.w += e3 * hp[192+lane];
  }
  unsigned short* co = combined + (size_t)w*HID + out_off;
  co[lane]     = f2bf(acc.x/(den.x+1e-16f) + bias[lane]);
  co[64+lane]  = f2bf(acc.y/(den.y+1e-16f) + bias[64+lane]);
  co[128+lane] = f2bf(acc.z/(den.z+1e-16f) + bias[128+lane]);
  co[192+lane] = f2bf(acc.w/(den.w+1e-16f) + bias[192+lane]);
}

// ---------- batchnorm ----------
__global__ __launch_bounds__(512) void k_bn_stats(const float* __restrict__ fused, int N,
                                                  float* __restrict__ gsum, float* __restrict__ gsq){
  int c = threadIdx.x;
  int rows_per = (N + gridDim.x - 1) / gridDim.x;
  int r0 = blockIdx.x * rows_per;
  int r1 = min(N, r0 + rows_per);
  float s = 0.f, q = 0.f;
  for(int r=r0; r<r1; r++){
    float v = fused[(size_t)r*HID + c];
    s += v; q += v*v;
  }
  atomicAdd(&gsum[c], s);
  atomicAdd(&gsq[c], q);
}

__global__ __launch_bounds__(512) void k_bn_final(const float* __restrict__ gsum, const float* __restrict__ gsq,
    const float* __restrict__ gamma, const float* __restrict__ beta,
    float* __restrict__ scale, float* __restrict__ shift, int N){
  int c = threadIdx.x;
  float mean = gsum[c] / (float)N;
  float var  = gsq[c] / (float)N - mean*mean;
  float sc = gamma[c] * rsqrtf(var + 1e-5f);
  scale[c] = sc;
  shift[c] = beta[c] - mean*sc;
}

__global__ void k_bn_apply(const float4* __restrict__ fused4, const float4* __restrict__ scale4,
                           const float4* __restrict__ shift4, float4* __restrict__ out4, long n4){
  long i = (long)blockIdx.x*blockDim.x + threadIdx.x;
  long stride = (long)gridDim.x*blockDim.x;
  for(long j=i; j<n4; j+=stride){
    float4 v = fused4[j];
    int c4 = (int)(j & 127);
    float4 sc = scale4[c4], sh = shift4[c4];
    float4 r;
    r.x = fmaxf(v.x*sc.x + sh.x, 0.f);
    r.y = fmaxf(v.y*sc.y + sh.y, 0.f);
    r.z = fmaxf(v.z*sc.z + sh.z, 0.f);
    r.w = fmaxf(v.w*sc.w + sh.w, 0.f);
    out4[j] = r;
  }
}

// ---------- host ----------
extern "C" void kernel_launch(void* const* d_in, const int* in_sizes, int n_in,
                              void* d_out, int out_size, void* d_ws, size_t ws_size,
                              hipStream_t stream){
  const float* x        = (const float*)d_in[0];
  const int*   ei32     = (const int*)  d_in[1];
  const float* W_f      = (const float*)d_in[2];
  const float* att_sf   = (const float*)d_in[3];
  const float* att_df   = (const float*)d_in[4];
  const float* bias_f   = (const float*)d_in[5];
  const float* W_b      = (const float*)d_in[6];
  const float* att_sb   = (const float*)d_in[7];
  const float* att_db   = (const float*)d_in[8];
  const float* bias_b   = (const float*)d_in[9];
  const float* W_fuse   = (const float*)d_in[10];
  const float* b_fuse   = (const float*)d_in[11];
  const float* bn_gamma = (const float*)d_in[12];
  const float* bn_beta  = (const float*)d_in[13];

  const int N = in_sizes[0] / 512;
  const int E = in_sizes[1] / 2;
  const int Mp = ((N + 127) / 128) * 128;   // row-padded for GEMM staging reads

  char* ws = (char*)d_ws;
  size_t off = 0;
  auto alloc = [&](size_t bytes)->char*{
    char* p = ws + off;
    off = (off + bytes + 255) & ~(size_t)255;
    return p;
  };

  int*   srcI   = (int*)  alloc((size_t)E*4);
  int*   dstI   = (int*)  alloc((size_t)E*4);
  unsigned short* xb      = (unsigned short*)alloc((size_t)Mp*KDIM*2);
  unsigned short* Wcat_t  = (unsigned short*)alloc((size_t)HID*KDIM*2);
  unsigned short* Wfuse_t = (unsigned short*)alloc((size_t)HID*KDIM*2);
  float* h      = (float*)alloc((size_t)N*HID*4);    // fwd|bwd; later aliased as `fused`
  float4* asf   = (float4*)alloc((size_t)N*16);
  float4* adf   = (float4*)alloc((size_t)N*16);
  float4* asb   = (float4*)alloc((size_t)N*16);
  float4* adb   = (float4*)alloc((size_t)N*16);
  float4* e_f   = (float4*)alloc((size_t)E*16);
  float4* e_b   = (float4*)alloc((size_t)E*16);
  int*   rsD    = (int*)  alloc((size_t)(N+1)*4);
  int*   curD   = (int*)  alloc((size_t)N*4);
  int*   listD  = (int*)  alloc((size_t)E*4);
  int*   rsS    = (int*)  alloc((size_t)(N+1)*4);
  int*   curS   = (int*)  alloc((size_t)N*4);
  int*   listS  = (int*)  alloc((size_t)E*4);
  unsigned short* combined = (unsigned short*)alloc((size_t)Mp*HID*2);
  float* gsum   = (float*)alloc(HID*4);
  float* gsq    = (float*)alloc(HID*4);
  float* scale  = (float*)alloc(HID*4);
  float* shift  = (float*)alloc(HID*4);
  int*   flag   = (int*)  alloc(4);
  float* fused  = h;   // alias: h dead after aggregation

  k_zero<<<256, 256, 0, stream>>>((int*)curD, (int*)curS, gsum, gsq, N);
  k_detect<<<1, 256, 0, stream>>>(ei32, flag);
  k_convert<<<(E+255)/256, 256, 0, stream>>>(ei32, flag, srcI, dstI, E);

  // bf16 conversions: x and the three weight matrices (transposed to [n][k])
  long xn4 = (long)N * KDIM / 4;
  k_cvt_x<<<2048, 256, 0, stream>>>((const float4*)x, (uint2*)xb, xn4);
  k_transcvt<<<(HC*KDIM+255)/256, 256, 0, stream>>>(W_f, Wcat_t, KDIM, HC);
  k_transcvt<<<(HC*KDIM+255)/256, 256, 0, stream>>>(W_b, Wcat_t + (size_t)HC*KDIM, KDIM, HC);
  k_transcvt<<<(HID*KDIM+255)/256, 256, 0, stream>>>(W_fuse, Wfuse_t, KDIM, HID);

  // h[N,512] = x @ [W_f | W_b]
  k_gemm_mfma<<<dim3(HID/128, Mp/128), 256, 0, stream>>>(xb, Wcat_t, h, N, HID, KDIM, nullptr);

  int nodeBlocks = (N + 3) / 4;
  k_att<<<nodeBlocks, 256, 0, stream>>>(h, att_sf, att_df, att_sb, att_db,
                                        asf, adf, asb, adb, N);

  k_edge<<<(E+255)/256, 256, 0, stream>>>(srcI, dstI, asf, adf, asb, adb,
                                          e_f, e_b, curD, curS, E);

  k_scan<<<1, 1024, 0, stream>>>(curD, N, rsD, curD);
  k_scan<<<1, 1024, 0, stream>>>(curS, N, rsS, curS);

  k_scatter<<<(E+255)/256, 256, 0, stream>>>(srcI, dstI, curD, curS, listD, listS, E);

  // fwd: segments by dst, gather h_f[src] (cols 0..255); bwd: by src, gather h_b[dst] (cols 256..511)
  k_agg<<<nodeBlocks, 256, 0, stream>>>(rsD, listD, e_f, srcI, h, 0,   bias_f, combined, N, 0);
  k_agg<<<nodeBlocks, 256, 0, stream>>>(rsS, listS, e_b, dstI, h, 256, bias_b, combined, N, HC);

  // fused = combined @ W_fuse + b_fuse  (writes over dead h region)
  k_gemm_mfma<<<dim3(HID/128, Mp/128), 256, 0, stream>>>(combined, Wfuse_t, fused, N, HID, KDIM, b_fuse);

  k_bn_stats<<<128, 512, 0, stream>>>(fused, N, gsum, gsq);
  k_bn_final<<<1, 512, 0, stream>>>(gsum, gsq, bn_gamma, bn_beta, scale, shift, N);
  long n4 = (long)N * HID / 4;
  k_bn_apply<<<2048, 256, 0, stream>>>((const float4*)fused, (const float4*)scale,
                                       (const float4*)shift, (float4*)d_out, n4);

  (void)n_in; (void)out_size; (void)ws_size;
}

// Round 6
// 1033.861 us; speedup vs baseline: 2.0892x; 1.2071x over previous
//
#include <hip/hip_runtime.h>
#include <math.h>

#define HEADS 4
#define CH 64
#define HC 256    // per-direction output channels
#define HID 512
#define KDIM 512

typedef __attribute__((ext_vector_type(8))) short short8;
typedef __attribute__((ext_vector_type(4))) float f32x4;

__device__ __forceinline__ float lrelu(float x){ return x > 0.f ? x : 0.2f*x; }

__device__ __forceinline__ unsigned short f2bf(float f){
  unsigned u = __float_as_uint(f);
  unsigned r = (u + 0x7FFFu + ((u >> 16) & 1u)) >> 16;
  return (unsigned short)r;
}
__device__ __forceinline__ float bf2f(unsigned short u){
  return __uint_as_float(((unsigned)u) << 16);
}

// ---------- init ----------
__global__ void k_zero(int* cntD, int* cntS, float* gsum, float* gsq, int N){
  int i = blockIdx.x*blockDim.x + threadIdx.x;
  int stride = gridDim.x*blockDim.x;
  for(int j=i; j<N; j+=stride){ cntD[j]=0; cntS[j]=0; }
  if(i < HID){ gsum[i]=0.f; gsq[i]=0.f; }
}

// ---------- edge dtype detect / convert ----------
__global__ void k_detect(const int* __restrict__ ei32, int* flag){
  __shared__ int any;
  if(threadIdx.x==0) any = 0;
  __syncthreads();
  int v = 0;
  for(int i=threadIdx.x; i<1024; i+=blockDim.x) v |= ei32[2*i+1];
  if(v) atomicOr(&any, 1);
  __syncthreads();
  if(threadIdx.x==0) *flag = (any==0) ? 1 : 0;   // 1 => buffer is int64
}

__global__ void k_convert(const int* __restrict__ ei32, const int* __restrict__ flag,
                          int* __restrict__ src, int* __restrict__ dst, int E){
  int i = blockIdx.x*blockDim.x + threadIdx.x;
  if(i>=E) return;
  if(*flag){ src[i] = ei32[2*i];  dst[i] = ei32[2*(E+i)]; }
  else     { src[i] = ei32[i];    dst[i] = ei32[E+i];     }
}

// ---------- f32 -> bf16 row-copy (x) ----------
__global__ void k_cvt_x(const float4* __restrict__ in4, uint2* __restrict__ out2, long n4){
  long i = (long)blockIdx.x*blockDim.x + threadIdx.x;
  long stride = (long)gridDim.x*blockDim.x;
  for(long j=i; j<n4; j+=stride){
    float4 v = in4[j];
    uint2 o;
    o.x = (unsigned)f2bf(v.x) | ((unsigned)f2bf(v.y) << 16);
    o.y = (unsigned)f2bf(v.z) | ((unsigned)f2bf(v.w) << 16);
    out2[j] = o;
  }
}

// ---------- transpose+convert weights: dst[n][k] = src[k][n], bf16 ----------
__global__ void k_transcvt(const float* __restrict__ src, unsigned short* __restrict__ dst,
                           int K, int C){
  int i = blockIdx.x*blockDim.x + threadIdx.x;
  if(i >= C*K) return;
  int n = i / K;
  int k = i - n*K;
  dst[(size_t)n*K + k] = f2bf(src[(size_t)k*C + n]);
}

// ---------- bf16 MFMA GEMM: C = A[Mp,K] @ Bt[Nc,K]^T (+bias); bf16 or f32 out ----------
__global__ __launch_bounds__(256) void k_gemm_mfma(
    const unsigned short* __restrict__ A,   // [Mp][K] bf16 row-major
    const unsigned short* __restrict__ Bt,  // [Nc][K] bf16 row-major
    float* __restrict__ Cf, unsigned short* __restrict__ Cb,
    int M, int Nc, int K, const float* __restrict__ bias){
  __shared__ __align__(16) unsigned short Asm[128*32];
  __shared__ __align__(16) unsigned short Bsm[128*32];
  int tid = threadIdx.x;
  int w = tid >> 6, lane = tid & 63;
  int wr = (w >> 1) * 64, wc = (w & 1) * 64;
  int lcol = lane & 15, lkb = lane >> 4;
  int row0 = blockIdx.y * 128, col0 = blockIdx.x * 128;

  int c0 = tid, c1 = tid + 256;
  int ar0 = c0 >> 2, ak0 = (c0 & 3) * 8;
  int ar1 = c1 >> 2, ak1 = (c1 & 3) * 8;

  f32x4 acc[4][4] = {};

  for(int kt = 0; kt < K; kt += 32){
    short8 va0 = *(const short8*)(A  + (size_t)(row0 + ar0)*K + kt + ak0);
    short8 va1 = *(const short8*)(A  + (size_t)(row0 + ar1)*K + kt + ak1);
    short8 vb0 = *(const short8*)(Bt + (size_t)(col0 + ar0)*K + kt + ak0);
    short8 vb1 = *(const short8*)(Bt + (size_t)(col0 + ar1)*K + kt + ak1);
    __syncthreads();
    *(short8*)(Asm + ar0*32 + ak0) = va0;
    *(short8*)(Asm + ar1*32 + ak1) = va1;
    *(short8*)(Bsm + ar0*32 + ak0) = vb0;
    *(short8*)(Bsm + ar1*32 + ak1) = vb1;
    __syncthreads();

    short8 af[4], bfr[4];
    #pragma unroll
    for(int mi=0; mi<4; mi++)
      af[mi] = *(const short8*)(Asm + (wr + mi*16 + lcol)*32 + lkb*8);
    #pragma unroll
    for(int ni=0; ni<4; ni++)
      bfr[ni] = *(const short8*)(Bsm + (wc + ni*16 + lcol)*32 + lkb*8);
    #pragma unroll
    for(int mi=0; mi<4; mi++)
      #pragma unroll
      for(int ni=0; ni<4; ni++)
        acc[mi][ni] = __builtin_amdgcn_mfma_f32_16x16x32_bf16(af[mi], bfr[ni], acc[mi][ni], 0, 0, 0);
  }

  int lr = (lane >> 4) * 4;
  #pragma unroll
  for(int mi=0; mi<4; mi++){
    int gr0 = row0 + wr + mi*16 + lr;
    #pragma unroll
    for(int ni=0; ni<4; ni++){
      int gc = col0 + wc + ni*16 + lcol;
      float bv = bias ? bias[gc] : 0.f;
      #pragma unroll
      for(int r=0; r<4; r++){
        int gr = gr0 + r;
        if(gr < M){
          float v = acc[mi][ni][r] + bv;
          if(Cb) Cb[(size_t)gr*Nc + gc] = f2bf(v);
          else   Cf[(size_t)gr*Nc + gc] = v;
        }
      }
    }
  }
}

// ---------- per-node attention dots (h bf16 [N][512]: fwd 0..255, bwd 256..511) ----------
__global__ __launch_bounds__(256) void k_att(
    const unsigned short* __restrict__ h,
    const float* __restrict__ att_sf, const float* __restrict__ att_df,
    const float* __restrict__ att_sb, const float* __restrict__ att_db,
    float4* __restrict__ asf, float4* __restrict__ adf,
    float4* __restrict__ asb, float4* __restrict__ adb, int N){
  int w = (blockIdx.x*(blockDim.x>>6)) + (threadIdx.x>>6);
  int lane = threadIdx.x & 63;
  if(w >= N) return;
  float psf[4], pdf_[4], psb[4], pdb_[4];
  #pragma unroll
  for(int i=0;i<4;i++){
    float vf = bf2f(h[(size_t)w*HID + i*64 + lane]);
    float vb = bf2f(h[(size_t)w*HID + 256 + i*64 + lane]);
    psf[i]  = vf*att_sf[i*64+lane];  pdf_[i] = vf*att_df[i*64+lane];
    psb[i]  = vb*att_sb[i*64+lane];  pdb_[i] = vb*att_db[i*64+lane];
  }
  #pragma unroll
  for(int off=32; off; off>>=1){
    #pragma unroll
    for(int i=0;i<4;i++){
      psf[i]  += __shfl_xor(psf[i],  off);
      pdf_[i] += __shfl_xor(pdf_[i], off);
      psb[i]  += __shfl_xor(psb[i],  off);
      pdb_[i] += __shfl_xor(pdb_[i], off);
    }
  }
  if(lane==0){
    asf[w] = make_float4(psf[0],psf[1],psf[2],psf[3]);
    adf[w] = make_float4(pdf_[0],pdf_[1],pdf_[2],pdf_[3]);
    asb[w] = make_float4(psb[0],psb[1],psb[2],psb[3]);
    adb[w] = make_float4(pdb_[0],pdb_[1],pdb_[2],pdb_[3]);
  }
}

// ---------- per-edge logits + degree counts ----------
__global__ void k_edge(const int* __restrict__ src, const int* __restrict__ dst,
    const float4* __restrict__ asf, const float4* __restrict__ adf,
    const float4* __restrict__ asb, const float4* __restrict__ adb,
    float4* __restrict__ ef, float4* __restrict__ eb,
    int* __restrict__ cntD, int* __restrict__ cntS, int E){
  int e = blockIdx.x*blockDim.x + threadIdx.x;
  if(e>=E) return;
  int s = src[e], d = dst[e];
  float4 a = asf[s], b = adf[d], r;
  r.x = lrelu(a.x+b.x); r.y = lrelu(a.y+b.y); r.z = lrelu(a.z+b.z); r.w = lrelu(a.w+b.w);
  ef[e] = r;
  a = asb[d]; b = adb[s];
  r.x = lrelu(a.x+b.x); r.y = lrelu(a.y+b.y); r.z = lrelu(a.z+b.z); r.w = lrelu(a.w+b.w);
  eb[e] = r;
  atomicAdd(&cntD[d], 1);
  atomicAdd(&cntS[s], 1);
}

// ---------- hierarchical scan: phase 1 (per-block local exclusive scan) ----------
__global__ __launch_bounds__(1024) void k_scan_local(
    const int* __restrict__ cntD, const int* __restrict__ cntS,
    int* __restrict__ rsD, int* __restrict__ curD,
    int* __restrict__ rsS, int* __restrict__ curS,
    int* __restrict__ bsums, int n, int nb){
  const int* cnt = blockIdx.y ? cntS : cntD;
  int* rs  = blockIdx.y ? rsS  : rsD;
  int* cur = blockIdx.y ? curS : curD;
  int* bs  = bsums + blockIdx.y*nb;
  __shared__ int sh[1024];
  int i = blockIdx.x*1024 + threadIdx.x;
  int v = (i<n) ? cnt[i] : 0;
  sh[threadIdx.x] = v;
  __syncthreads();
  for(int off=1; off<1024; off<<=1){
    int t = (threadIdx.x>=off) ? sh[threadIdx.x-off] : 0;
    __syncthreads();
    sh[threadIdx.x] += t;
    __syncthreads();
  }
  if(i<n){ int e0 = sh[threadIdx.x] - v; rs[i] = e0; cur[i] = e0; }
  if(threadIdx.x==1023) bs[blockIdx.x] = sh[1023];
}

// ---------- phase 2: exclusive scan of block sums (nb <= 256) ----------
__global__ __launch_bounds__(256) void k_scan_bsums(int* __restrict__ bsums,
                                                    int* __restrict__ totals, int nb){
  int* bs = bsums + blockIdx.x*nb;
  __shared__ int sh[256];
  int v = (threadIdx.x < nb) ? bs[threadIdx.x] : 0;
  sh[threadIdx.x] = v;
  __syncthreads();
  for(int off=1; off<256; off<<=1){
    int t = (threadIdx.x>=off) ? sh[threadIdx.x-off] : 0;
    __syncthreads();
    sh[threadIdx.x] += t;
    __syncthreads();
  }
  if(threadIdx.x < nb) bs[threadIdx.x] = sh[threadIdx.x] - v;
  if(threadIdx.x == 255) totals[blockIdx.x] = sh[255];
}

// ---------- phase 3: add block offsets ----------
__global__ __launch_bounds__(1024) void k_scan_add(
    int* __restrict__ rsD, int* __restrict__ curD,
    int* __restrict__ rsS, int* __restrict__ curS,
    const int* __restrict__ bsums, const int* __restrict__ totals, int n, int nb){
  const int* bs = bsums + blockIdx.y*nb;
  int* rs  = blockIdx.y ? rsS  : rsD;
  int* cur = blockIdx.y ? curS : curD;
  int add = bs[blockIdx.x];
  int i = blockIdx.x*1024 + threadIdx.x;
  if(i<n){ rs[i] += add; cur[i] += add; }
  if(i==0) rs[n] = totals[blockIdx.y];
}

// ---------- scatter edges into CSR order ----------
__global__ void k_scatter(const int* __restrict__ src, const int* __restrict__ dst,
    int* __restrict__ curD, int* __restrict__ curS,
    int* __restrict__ listD, int* __restrict__ listS, int E){
  int e = blockIdx.x*blockDim.x + threadIdx.x;
  if(e>=E) return;
  int p = atomicAdd(&curD[dst[e]], 1);  listD[p] = e;
  int q = atomicAdd(&curS[src[e]], 1);  listS[q] = e;
}

// ---------- per-node softmax + weighted aggregation (bf16 h gather) ----------
__global__ __launch_bounds__(256) void k_agg(
    const int* __restrict__ rs, const int* __restrict__ list,
    const float4* __restrict__ etab, const int* __restrict__ gidx,
    const unsigned short* __restrict__ h, int hoff, const float* __restrict__ bias,
    unsigned short* __restrict__ combined, int N, int out_off){
  int w = (blockIdx.x*(blockDim.x>>6)) + (threadIdx.x>>6);
  int lane = threadIdx.x & 63;
  if(w >= N) return;
  int beg = rs[w], end = rs[w+1];
  float4 m = make_float4(-1e30f,-1e30f,-1e30f,-1e30f);
  for(int j=beg+lane; j<end; j+=64){
    float4 ev = etab[list[j]];
    m.x = fmaxf(m.x, ev.x); m.y = fmaxf(m.y, ev.y);
    m.z = fmaxf(m.z, ev.z); m.w = fmaxf(m.w, ev.w);
  }
  #pragma unroll
  for(int off=32; off; off>>=1){
    m.x = fmaxf(m.x, __shfl_xor(m.x, off));
    m.y = fmaxf(m.y, __shfl_xor(m.y, off));
    m.z = fmaxf(m.z, __shfl_xor(m.z, off));
    m.w = fmaxf(m.w, __shfl_xor(m.w, off));
  }
  float4 acc = make_float4(0,0,0,0);
  float4 den = make_float4(0,0,0,0);
  for(int j=beg; j<end; j++){
    int e = list[j];
    float4 ev = etab[e];
    int g = gidx[e];
    const unsigned short* hp = h + (size_t)g*HID + hoff;
    float e0 = __expf(ev.x - m.x), e1 = __expf(ev.y - m.y);
    float e2 = __expf(ev.z - m.z), e3 = __expf(ev.w - m.w);
    den.x += e0; den.y += e1; den.z += e2; den.w += e3;
    acc.x += e0 * bf2f(hp[lane]);
    acc.y += e1 * bf2f(hp[64+lane]);
    acc.z += e2 * bf2f(hp[128+lane]);
    acc.w += e3 * bf2f(hp[192+lane]);
  }
  unsigned short* co = combined + (size_t)w*HID + out_off;
  co[lane]     = f2bf(acc.x/(den.x+1e-16f) + bias[lane]);
  co[64+lane]  = f2bf(acc.y/(den.y+1e-16f) + bias[64+lane]);
  co[128+lane] = f2bf(acc.z/(den.z+1e-16f) + bias[128+lane]);
  co[192+lane] = f2bf(acc.w/(den.w+1e-16f) + bias[192+lane]);
}

// ---------- batchnorm (bf16 fused input) ----------
__global__ __launch_bounds__(512) void k_bn_stats(const unsigned short* __restrict__ fused, int N,
                                                  float* __restrict__ gsum, float* __restrict__ gsq){
  int c = threadIdx.x;
  int rows_per = (N + gridDim.x - 1) / gridDim.x;
  int r0 = blockIdx.x * rows_per;
  int r1 = min(N, r0 + rows_per);
  float s = 0.f, q = 0.f;
  for(int r=r0; r<r1; r++){
    float v = bf2f(fused[(size_t)r*HID + c]);
    s += v; q += v*v;
  }
  atomicAdd(&gsum[c], s);
  atomicAdd(&gsq[c], q);
}

__global__ __launch_bounds__(512) void k_bn_final(const float* __restrict__ gsum, const float* __restrict__ gsq,
    const float* __restrict__ gamma, const float* __restrict__ beta,
    float* __restrict__ scale, float* __restrict__ shift, int N){
  int c = threadIdx.x;
  float mean = gsum[c] / (float)N;
  float var  = gsq[c] / (float)N - mean*mean;
  float sc = gamma[c] * rsqrtf(var + 1e-5f);
  scale[c] = sc;
  shift[c] = beta[c] - mean*sc;
}

__global__ void k_bn_apply(const uint2* __restrict__ fused2, const float4* __restrict__ scale4,
                           const float4* __restrict__ shift4, float4* __restrict__ out4, long n4){
  long i = (long)blockIdx.x*blockDim.x + threadIdx.x;
  long stride = (long)gridDim.x*blockDim.x;
  for(long j=i; j<n4; j+=stride){
    uint2 u = fused2[j];
    int c4 = (int)(j & 127);
    float4 sc = scale4[c4], sh = shift4[c4];
    float4 r;
    r.x = fmaxf(__uint_as_float(u.x << 16)          * sc.x + sh.x, 0.f);
    r.y = fmaxf(__uint_as_float(u.x & 0xffff0000u)  * sc.y + sh.y, 0.f);
    r.z = fmaxf(__uint_as_float(u.y << 16)          * sc.z + sh.z, 0.f);
    r.w = fmaxf(__uint_as_float(u.y & 0xffff0000u)  * sc.w + sh.w, 0.f);
    out4[j] = r;
  }
}

// ---------- host ----------
extern "C" void kernel_launch(void* const* d_in, const int* in_sizes, int n_in,
                              void* d_out, int out_size, void* d_ws, size_t ws_size,
                              hipStream_t stream){
  const float* x        = (const float*)d_in[0];
  const int*   ei32     = (const int*)  d_in[1];
  const float* W_f      = (const float*)d_in[2];
  const float* att_sf   = (const float*)d_in[3];
  const float* att_df   = (const float*)d_in[4];
  const float* bias_f   = (const float*)d_in[5];
  const float* W_b      = (const float*)d_in[6];
  const float* att_sb   = (const float*)d_in[7];
  const float* att_db   = (const float*)d_in[8];
  const float* bias_b   = (const float*)d_in[9];
  const float* W_fuse   = (const float*)d_in[10];
  const float* b_fuse   = (const float*)d_in[11];
  const float* bn_gamma = (const float*)d_in[12];
  const float* bn_beta  = (const float*)d_in[13];

  const int N = in_sizes[0] / 512;
  const int E = in_sizes[1] / 2;
  const int Mp = ((N + 127) / 128) * 128;
  const int nb = (N + 1023) / 1024;

  char* ws = (char*)d_ws;
  size_t off = 0;
  auto alloc = [&](size_t bytes)->char*{
    char* p = ws + off;
    off = (off + bytes + 255) & ~(size_t)255;
    return p;
  };

  int*   srcI   = (int*)  alloc((size_t)E*4);
  int*   dstI   = (int*)  alloc((size_t)E*4);
  unsigned short* xb      = (unsigned short*)alloc((size_t)Mp*KDIM*2);
  unsigned short* Wcat_t  = (unsigned short*)alloc((size_t)HID*KDIM*2);
  unsigned short* Wfuse_t = (unsigned short*)alloc((size_t)HID*KDIM*2);
  unsigned short* h       = (unsigned short*)alloc((size_t)Mp*HID*2);  // later aliased as fused
  float4* asf   = (float4*)alloc((size_t)N*16);
  float4* adf   = (float4*)alloc((size_t)N*16);
  float4* asb   = (float4*)alloc((size_t)N*16);
  float4* adb   = (float4*)alloc((size_t)N*16);
  float4* e_f   = (float4*)alloc((size_t)E*16);
  float4* e_b   = (float4*)alloc((size_t)E*16);
  int*   rsD    = (int*)  alloc((size_t)(N+1)*4);
  int*   curD   = (int*)  alloc((size_t)N*4);
  int*   listD  = (int*)  alloc((size_t)E*4);
  int*   rsS    = (int*)  alloc((size_t)(N+1)*4);
  int*   curS   = (int*)  alloc((size_t)N*4);
  int*   listS  = (int*)  alloc((size_t)E*4);
  unsigned short* combined = (unsigned short*)alloc((size_t)Mp*HID*2);
  float* gsum   = (float*)alloc(HID*4);
  float* gsq    = (float*)alloc(HID*4);
  float* scale  = (float*)alloc(HID*4);
  float* shift  = (float*)alloc(HID*4);
  int*   bsums  = (int*)  alloc(2*256*4);
  int*   totals = (int*)  alloc(2*4);
  int*   flag   = (int*)  alloc(4);
  unsigned short* fused = h;   // alias: h dead after aggregation

  k_zero<<<256, 256, 0, stream>>>((int*)curD, (int*)curS, gsum, gsq, N);
  k_detect<<<1, 256, 0, stream>>>(ei32, flag);
  k_convert<<<(E+255)/256, 256, 0, stream>>>(ei32, flag, srcI, dstI, E);

  long xn4 = (long)N * KDIM / 4;
  k_cvt_x<<<2048, 256, 0, stream>>>((const float4*)x, (uint2*)xb, xn4);
  k_transcvt<<<(HC*KDIM+255)/256, 256, 0, stream>>>(W_f, Wcat_t, KDIM, HC);
  k_transcvt<<<(HC*KDIM+255)/256, 256, 0, stream>>>(W_b, Wcat_t + (size_t)HC*KDIM, KDIM, HC);
  k_transcvt<<<(HID*KDIM+255)/256, 256, 0, stream>>>(W_fuse, Wfuse_t, KDIM, HID);

  // h[N,512](bf16) = x @ [W_f | W_b]
  k_gemm_mfma<<<dim3(HID/128, Mp/128), 256, 0, stream>>>(xb, Wcat_t, nullptr, h, N, HID, KDIM, nullptr);

  int nodeBlocks = (N + 3) / 4;
  k_att<<<nodeBlocks, 256, 0, stream>>>(h, att_sf, att_df, att_sb, att_db,
                                        asf, adf, asb, adb, N);

  k_edge<<<(E+255)/256, 256, 0, stream>>>(srcI, dstI, asf, adf, asb, adb,
                                          e_f, e_b, curD, curS, E);

  k_scan_local<<<dim3(nb,2), 1024, 0, stream>>>(curD, curS, rsD, curD, rsS, curS, bsums, N, nb);
  k_scan_bsums<<<2, 256, 0, stream>>>(bsums, totals, nb);
  k_scan_add<<<dim3(nb,2), 1024, 0, stream>>>(rsD, curD, rsS, curS, bsums, totals, N, nb);

  k_scatter<<<(E+255)/256, 256, 0, stream>>>(srcI, dstI, curD, curS, listD, listS, E);

  // fwd: segments by dst, gather h[src] cols 0..255; bwd: by src, gather h[dst] cols 256..511
  k_agg<<<nodeBlocks, 256, 0, stream>>>(rsD, listD, e_f, srcI, h, 0,   bias_f, combined, N, 0);
  k_agg<<<nodeBlocks, 256, 0, stream>>>(rsS, listS, e_b, dstI, h, 256, bias_b, combined, N, HC);

  // fused(bf16) = combined @ W_fuse + b_fuse  (overwrites dead h)
  k_gemm_mfma<<<dim3(HID/128, Mp/128), 256, 0, stream>>>(combined, Wfuse_t, nullptr, fused, N, HID, KDIM, b_fuse);

  k_bn_stats<<<128, 512, 0, stream>>>(fused, N, gsum, gsq);
  k_bn_final<<<1, 512, 0, stream>>>(gsum, gsq, bn_gamma, bn_beta, scale, shift, N);
  long n4 = (long)N * HID / 4;
  k_bn_apply<<<2048, 256, 0, stream>>>((const uint2*)fused, (const float4*)scale,
                                       (const float4*)shift, (float4*)d_out, n4);

  (void)n_in; (void)out_size; (void)ws_size;
}

// Round 10
// 943.671 us; speedup vs baseline: 2.2888x; 1.0956x over previous
//
#include <hip/hip_runtime.h>
#include <math.h>

#define HEADS 4
#define CH 64
#define HC 256    // per-direction output channels
#define HID 512
#define KDIM 512

typedef __attribute__((ext_vector_type(8))) short short8;
typedef __attribute__((ext_vector_type(4))) float f32x4;

__device__ __forceinline__ float lrelu(float x){ return x > 0.f ? x : 0.2f*x; }

__device__ __forceinline__ unsigned short f2bf(float f){
  unsigned u = __float_as_uint(f);
  unsigned r = (u + 0x7FFFu + ((u >> 16) & 1u)) >> 16;
  return (unsigned short)r;
}
__device__ __forceinline__ float bf2f(unsigned short u){
  return __uint_as_float(((unsigned)u) << 16);
}

// ---------- init ----------
__global__ void k_zero(int* cntD, int* cntS, float* gsum, float* gsq, int N){
  int i = blockIdx.x*blockDim.x + threadIdx.x;
  int stride = gridDim.x*blockDim.x;
  for(int j=i; j<N; j+=stride){ cntD[j]=0; cntS[j]=0; }
  if(i < HID){ gsum[i]=0.f; gsq[i]=0.f; }
}

// ---------- edge dtype detect ----------
__global__ void k_detect(const int* __restrict__ ei32, int* flag){
  __shared__ int any;
  if(threadIdx.x==0) any = 0;
  __syncthreads();
  int v = 0;
  for(int i=threadIdx.x; i<1024; i+=blockDim.x) v |= ei32[2*i+1];
  if(v) atomicOr(&any, 1);
  __syncthreads();
  if(threadIdx.x==0) *flag = (any==0) ? 1 : 0;   // 1 => buffer is int64
}

// ---------- convert + degree counting (k_edge folded in) ----------
__global__ void k_convert(const int* __restrict__ ei32, const int* __restrict__ flag,
                          int* __restrict__ src, int* __restrict__ dst,
                          int* __restrict__ cntD, int* __restrict__ cntS, int E){
  int i = blockIdx.x*blockDim.x + threadIdx.x;
  if(i>=E) return;
  int s, d;
  if(*flag){ s = ei32[2*i];  d = ei32[2*(E+i)]; }
  else     { s = ei32[i];    d = ei32[E+i];     }
  src[i] = s; dst[i] = d;
  atomicAdd(&cntD[d], 1);
  atomicAdd(&cntS[s], 1);
}

// ---------- f32 -> bf16 row-copy (x) ----------
__global__ void k_cvt_x(const float4* __restrict__ in4, uint2* __restrict__ out2, long n4){
  long i = (long)blockIdx.x*blockDim.x + threadIdx.x;
  long stride = (long)gridDim.x*blockDim.x;
  for(long j=i; j<n4; j+=stride){
    float4 v = in4[j];
    uint2 o;
    o.x = (unsigned)f2bf(v.x) | ((unsigned)f2bf(v.y) << 16);
    o.y = (unsigned)f2bf(v.z) | ((unsigned)f2bf(v.w) << 16);
    out2[j] = o;
  }
}

// ---------- transpose+convert weights: dst[n][k] = src[k][n], bf16 ----------
__global__ void k_transcvt(const float* __restrict__ src, unsigned short* __restrict__ dst,
                           int K, int C){
  int i = blockIdx.x*blockDim.x + threadIdx.x;
  if(i >= C*K) return;
  int n = i / K;
  int k = i - n*K;
  dst[(size_t)n*K + k] = f2bf(src[(size_t)k*C + n]);
}

// ---------- bf16 MFMA GEMM: C = A[Mp,K] @ Bt[Nc,K]^T (+bias); bf16 or f32 out ----------
__global__ __launch_bounds__(256) void k_gemm_mfma(
    const unsigned short* __restrict__ A,   // [Mp][K] bf16 row-major
    const unsigned short* __restrict__ Bt,  // [Nc][K] bf16 row-major
    float* __restrict__ Cf, unsigned short* __restrict__ Cb,
    int M, int Nc, int K, const float* __restrict__ bias){
  __shared__ __align__(16) unsigned short Asm[128*32];
  __shared__ __align__(16) unsigned short Bsm[128*32];
  int tid = threadIdx.x;
  int w = tid >> 6, lane = tid & 63;
  int wr = (w >> 1) * 64, wc = (w & 1) * 64;
  int lcol = lane & 15, lkb = lane >> 4;
  int row0 = blockIdx.y * 128, col0 = blockIdx.x * 128;

  int c0 = tid, c1 = tid + 256;
  int ar0 = c0 >> 2, ak0 = (c0 & 3) * 8;
  int ar1 = c1 >> 2, ak1 = (c1 & 3) * 8;

  f32x4 acc[4][4] = {};

  for(int kt = 0; kt < K; kt += 32){
    short8 va0 = *(const short8*)(A  + (size_t)(row0 + ar0)*K + kt + ak0);
    short8 va1 = *(const short8*)(A  + (size_t)(row0 + ar1)*K + kt + ak1);
    short8 vb0 = *(const short8*)(Bt + (size_t)(col0 + ar0)*K + kt + ak0);
    short8 vb1 = *(const short8*)(Bt + (size_t)(col0 + ar1)*K + kt + ak1);
    __syncthreads();
    *(short8*)(Asm + ar0*32 + ak0) = va0;
    *(short8*)(Asm + ar1*32 + ak1) = va1;
    *(short8*)(Bsm + ar0*32 + ak0) = vb0;
    *(short8*)(Bsm + ar1*32 + ak1) = vb1;
    __syncthreads();

    short8 af[4], bfr[4];
    #pragma unroll
    for(int mi=0; mi<4; mi++)
      af[mi] = *(const short8*)(Asm + (wr + mi*16 + lcol)*32 + lkb*8);
    #pragma unroll
    for(int ni=0; ni<4; ni++)
      bfr[ni] = *(const short8*)(Bsm + (wc + ni*16 + lcol)*32 + lkb*8);
    #pragma unroll
    for(int mi=0; mi<4; mi++)
      #pragma unroll
      for(int ni=0; ni<4; ni++)
        acc[mi][ni] = __builtin_amdgcn_mfma_f32_16x16x32_bf16(af[mi], bfr[ni], acc[mi][ni], 0, 0, 0);
  }

  int lr = (lane >> 4) * 4;
  #pragma unroll
  for(int mi=0; mi<4; mi++){
    int gr0 = row0 + wr + mi*16 + lr;
    #pragma unroll
    for(int ni=0; ni<4; ni++){
      int gc = col0 + wc + ni*16 + lcol;
      float bv = bias ? bias[gc] : 0.f;
      #pragma unroll
      for(int r=0; r<4; r++){
        int gr = gr0 + r;
        if(gr < M){
          float v = acc[mi][ni][r] + bv;
          if(Cb) Cb[(size_t)gr*Nc + gc] = f2bf(v);
          else   Cf[(size_t)gr*Nc + gc] = v;
        }
      }
    }
  }
}

// ---------- per-node attention dots (h bf16 [N][512]: fwd 0..255, bwd 256..511) ----------
__global__ __launch_bounds__(256) void k_att(
    const unsigned short* __restrict__ h,
    const float* __restrict__ att_sf, const float* __restrict__ att_df,
    const float* __restrict__ att_sb, const float* __restrict__ att_db,
    float4* __restrict__ asf, float4* __restrict__ adf,
    float4* __restrict__ asb, float4* __restrict__ adb, int N){
  int w = (blockIdx.x*(blockDim.x>>6)) + (threadIdx.x>>6);
  int lane = threadIdx.x & 63;
  if(w >= N) return;
  float psf[4], pdf_[4], psb[4], pdb_[4];
  #pragma unroll
  for(int i=0;i<4;i++){
    float vf = bf2f(h[(size_t)w*HID + i*64 + lane]);
    float vb = bf2f(h[(size_t)w*HID + 256 + i*64 + lane]);
    psf[i]  = vf*att_sf[i*64+lane];  pdf_[i] = vf*att_df[i*64+lane];
    psb[i]  = vb*att_sb[i*64+lane];  pdb_[i] = vb*att_db[i*64+lane];
  }
  #pragma unroll
  for(int off=32; off; off>>=1){
    #pragma unroll
    for(int i=0;i<4;i++){
      psf[i]  += __shfl_xor(psf[i],  off);
      pdf_[i] += __shfl_xor(pdf_[i], off);
      psb[i]  += __shfl_xor(psb[i],  off);
      pdb_[i] += __shfl_xor(pdb_[i], off);
    }
  }
  if(lane==0){
    asf[w] = make_float4(psf[0],psf[1],psf[2],psf[3]);
    adf[w] = make_float4(pdf_[0],pdf_[1],pdf_[2],pdf_[3]);
    asb[w] = make_float4(psb[0],psb[1],psb[2],psb[3]);
    adb[w] = make_float4(pdb_[0],pdb_[1],pdb_[2],pdb_[3]);
  }
}

// ---------- hierarchical scan: phase 1 (per-block local exclusive scan) ----------
__global__ __launch_bounds__(1024) void k_scan_local(
    const int* __restrict__ cntD, const int* __restrict__ cntS,
    int* __restrict__ rsD, int* __restrict__ curD,
    int* __restrict__ rsS, int* __restrict__ curS,
    int* __restrict__ bsums, int n, int nb){
  const int* cnt = blockIdx.y ? cntS : cntD;
  int* rs  = blockIdx.y ? rsS  : rsD;
  int* cur = blockIdx.y ? curS : curD;
  int* bs  = bsums + blockIdx.y*nb;
  __shared__ int sh[1024];
  int i = blockIdx.x*1024 + threadIdx.x;
  int v = (i<n) ? cnt[i] : 0;
  sh[threadIdx.x] = v;
  __syncthreads();
  for(int off=1; off<1024; off<<=1){
    int t = (threadIdx.x>=off) ? sh[threadIdx.x-off] : 0;
    __syncthreads();
    sh[threadIdx.x] += t;
    __syncthreads();
  }
  if(i<n){ int e0 = sh[threadIdx.x] - v; rs[i] = e0; cur[i] = e0; }
  if(threadIdx.x==1023) bs[blockIdx.x] = sh[1023];
}

// ---------- phase 2: exclusive scan of block sums (nb <= 256) ----------
__global__ __launch_bounds__(256) void k_scan_bsums(int* __restrict__ bsums,
                                                    int* __restrict__ totals, int nb){
  int* bs = bsums + blockIdx.x*nb;
  __shared__ int sh[256];
  int v = (threadIdx.x < nb) ? bs[threadIdx.x] : 0;
  sh[threadIdx.x] = v;
  __syncthreads();
  for(int off=1; off<256; off<<=1){
    int t = (threadIdx.x>=off) ? sh[threadIdx.x-off] : 0;
    __syncthreads();
    sh[threadIdx.x] += t;
    __syncthreads();
  }
  if(threadIdx.x < nb) bs[threadIdx.x] = sh[threadIdx.x] - v;
  if(threadIdx.x == 255) totals[blockIdx.x] = sh[255];
}

// ---------- phase 3: add block offsets ----------
__global__ __launch_bounds__(1024) void k_scan_add(
    int* __restrict__ rsD, int* __restrict__ curD,
    int* __restrict__ rsS, int* __restrict__ curS,
    const int* __restrict__ bsums, const int* __restrict__ totals, int n, int nb){
  const int* bs = bsums + blockIdx.y*nb;
  int* rs  = blockIdx.y ? rsS  : rsD;
  int* cur = blockIdx.y ? curS : curD;
  int add = bs[blockIdx.x];
  int i = blockIdx.x*1024 + threadIdx.x;
  if(i<n){ rs[i] += add; cur[i] += add; }
  if(i==0) rs[n] = totals[blockIdx.y];
}

// ---------- scatter: write NEIGHBOR id as payload (listD[p]=src, listS[q]=dst) ----------
__global__ void k_scatter(const int* __restrict__ src, const int* __restrict__ dst,
    int* __restrict__ curD, int* __restrict__ curS,
    int* __restrict__ listD, int* __restrict__ listS, int E){
  int e = blockIdx.x*blockDim.x + threadIdx.x;
  if(e>=E) return;
  int s = src[e], d = dst[e];
  int p = atomicAdd(&curD[d], 1);  listD[p] = s;
  int q = atomicAdd(&curS[s], 1);  listS[q] = d;
}

// ---------- fused softmax+aggregate, both directions (grid.y), logits recomputed ----------
// dir 0 (fwd):  node w=dst, neighbor g=src: logit = lrelu(asf[g]+adf[w]); gather h[g][0:256);  out cols 0..255,  bias_f
// dir 1 (bwd):  node w=src, neighbor g=dst: logit = lrelu(asb[g]+adb[w]); gather h[g][256:512); out cols 256..511, bias_b
__global__ __launch_bounds__(256) void k_agg2(
    const int* __restrict__ rsD, const int* __restrict__ listD,
    const int* __restrict__ rsS, const int* __restrict__ listS,
    const float4* __restrict__ asf, const float4* __restrict__ adf,
    const float4* __restrict__ asb, const float4* __restrict__ adb,
    const unsigned short* __restrict__ h,
    const float* __restrict__ bias_f, const float* __restrict__ bias_b,
    unsigned short* __restrict__ combined, int N){
  int dir = blockIdx.y;
  const int* rs     = dir ? rsS   : rsD;
  const int* list   = dir ? listS : listD;
  const float4* At  = dir ? asb   : asf;
  const float4* Bt  = dir ? adb   : adf;
  const float* bias = dir ? bias_b : bias_f;
  int off256 = dir ? 256 : 0;

  int w = blockIdx.x*(blockDim.x>>6) + (threadIdx.x>>6);
  int lane = threadIdx.x & 63;
  if(w >= N) return;
  int beg = rs[w], end = rs[w+1];
  float4 bw = Bt[w];

  // per-head max (lanes stride edges)
  float4 m = make_float4(-1e30f,-1e30f,-1e30f,-1e30f);
  for(int j=beg+lane; j<end; j+=64){
    float4 a = At[list[j]];
    m.x = fmaxf(m.x, lrelu(a.x+bw.x));
    m.y = fmaxf(m.y, lrelu(a.y+bw.y));
    m.z = fmaxf(m.z, lrelu(a.z+bw.z));
    m.w = fmaxf(m.w, lrelu(a.w+bw.w));
  }
  #pragma unroll
  for(int off=32; off; off>>=1){
    m.x = fmaxf(m.x, __shfl_xor(m.x, off));
    m.y = fmaxf(m.y, __shfl_xor(m.y, off));
    m.z = fmaxf(m.z, __shfl_xor(m.z, off));
    m.w = fmaxf(m.w, __shfl_xor(m.w, off));
  }
  int head = lane >> 4;                     // lane owns cols lane*4..lane*4+3 (one head)
  float mh = head==0 ? m.x : head==1 ? m.y : head==2 ? m.z : m.w;
  float bh = head==0 ? bw.x : head==1 ? bw.y : head==2 ? bw.z : bw.w;

  const float* Atf = (const float*)At;
  float acc0=0.f, acc1=0.f, acc2=0.f, acc3=0.f, den=0.f;
  for(int j=beg; j<end; j++){
    int g = list[j];                                   // uniform
    float ah = Atf[(size_t)g*4 + head];                // 4B from hot table
    float eh = __expf(lrelu(ah + bh) - mh);
    den += eh;
    uint2 u = *(const uint2*)(h + (size_t)g*HID + off256 + lane*4);
    acc0 += eh * bf2f((unsigned short)(u.x & 0xffffu));
    acc1 += eh * __uint_as_float(u.x & 0xffff0000u);
    acc2 += eh * bf2f((unsigned short)(u.y & 0xffffu));
    acc3 += eh * __uint_as_float(u.y & 0xffff0000u);
  }
  float inv = 1.f / (den + 1e-16f);
  int c = lane*4;
  float o0 = acc0*inv + bias[c+0];
  float o1 = acc1*inv + bias[c+1];
  float o2 = acc2*inv + bias[c+2];
  float o3 = acc3*inv + bias[c+3];
  uint2 o;
  o.x = (unsigned)f2bf(o0) | ((unsigned)f2bf(o1) << 16);
  o.y = (unsigned)f2bf(o2) | ((unsigned)f2bf(o3) << 16);
  *(uint2*)(combined + (size_t)w*HID + off256 + c) = o;
}

// ---------- batchnorm (bf16 fused input) ----------
__global__ __launch_bounds__(512) void k_bn_stats(const unsigned short* __restrict__ fused, int N,
                                                  float* __restrict__ gsum, float* __restrict__ gsq){
  int c = threadIdx.x;
  int rows_per = (N + gridDim.x - 1) / gridDim.x;
  int r0 = blockIdx.x * rows_per;
  int r1 = min(N, r0 + rows_per);
  float s = 0.f, q = 0.f;
  for(int r=r0; r<r1; r++){
    float v = bf2f(fused[(size_t)r*HID + c]);
    s += v; q += v*v;
  }
  atomicAdd(&gsum[c], s);
  atomicAdd(&gsq[c], q);
}

__global__ __launch_bounds__(512) void k_bn_final(const float* __restrict__ gsum, const float* __restrict__ gsq,
    const float* __restrict__ gamma, const float* __restrict__ beta,
    float* __restrict__ scale, float* __restrict__ shift, int N){
  int c = threadIdx.x;
  float mean = gsum[c] / (float)N;
  float var  = gsq[c] / (float)N - mean*mean;
  float sc = gamma[c] * rsqrtf(var + 1e-5f);
  scale[c] = sc;
  shift[c] = beta[c] - mean*sc;
}

__global__ void k_bn_apply(const uint2* __restrict__ fused2, const float4* __restrict__ scale4,
                           const float4* __restrict__ shift4, float4* __restrict__ out4, long n4){
  long i = (long)blockIdx.x*blockDim.x + threadIdx.x;
  long stride = (long)gridDim.x*blockDim.x;
  for(long j=i; j<n4; j+=stride){
    uint2 u = fused2[j];
    int c4 = (int)(j & 127);
    float4 sc = scale4[c4], sh = shift4[c4];
    float4 r;
    r.x = fmaxf(__uint_as_float(u.x << 16)          * sc.x + sh.x, 0.f);
    r.y = fmaxf(__uint_as_float(u.x & 0xffff0000u)  * sc.y + sh.y, 0.f);
    r.z = fmaxf(__uint_as_float(u.y << 16)          * sc.z + sh.z, 0.f);
    r.w = fmaxf(__uint_as_float(u.y & 0xffff0000u)  * sc.w + sh.w, 0.f);
    out4[j] = r;
  }
}

// ---------- host ----------
extern "C" void kernel_launch(void* const* d_in, const int* in_sizes, int n_in,
                              void* d_out, int out_size, void* d_ws, size_t ws_size,
                              hipStream_t stream){
  const float* x        = (const float*)d_in[0];
  const int*   ei32     = (const int*)  d_in[1];
  const float* W_f      = (const float*)d_in[2];
  const float* att_sf   = (const float*)d_in[3];
  const float* att_df   = (const float*)d_in[4];
  const float* bias_f   = (const float*)d_in[5];
  const float* W_b      = (const float*)d_in[6];
  const float* att_sb   = (const float*)d_in[7];
  const float* att_db   = (const float*)d_in[8];
  const float* bias_b   = (const float*)d_in[9];
  const float* W_fuse   = (const float*)d_in[10];
  const float* b_fuse   = (const float*)d_in[11];
  const float* bn_gamma = (const float*)d_in[12];
  const float* bn_beta  = (const float*)d_in[13];

  const int N = in_sizes[0] / 512;
  const int E = in_sizes[1] / 2;
  const int Mp = ((N + 127) / 128) * 128;
  const int nb = (N + 1023) / 1024;

  char* ws = (char*)d_ws;
  size_t off = 0;
  auto alloc = [&](size_t bytes)->char*{
    char* p = ws + off;
    off = (off + bytes + 255) & ~(size_t)255;
    return p;
  };

  int*   srcI   = (int*)  alloc((size_t)E*4);
  int*   dstI   = (int*)  alloc((size_t)E*4);
  unsigned short* xb      = (unsigned short*)alloc((size_t)Mp*KDIM*2);
  unsigned short* Wcat_t  = (unsigned short*)alloc((size_t)HID*KDIM*2);
  unsigned short* Wfuse_t = (unsigned short*)alloc((size_t)HID*KDIM*2);
  unsigned short* h       = (unsigned short*)alloc((size_t)Mp*HID*2);  // later aliased as fused
  float4* asf   = (float4*)alloc((size_t)N*16);
  float4* adf   = (float4*)alloc((size_t)N*16);
  float4* asb   = (float4*)alloc((size_t)N*16);
  float4* adb   = (float4*)alloc((size_t)N*16);
  int*   rsD    = (int*)  alloc((size_t)(N+1)*4);
  int*   curD   = (int*)  alloc((size_t)N*4);
  int*   listD  = (int*)  alloc((size_t)E*4);
  int*   rsS    = (int*)  alloc((size_t)(N+1)*4);
  int*   curS   = (int*)  alloc((size_t)N*4);
  int*   listS  = (int*)  alloc((size_t)E*4);
  unsigned short* combined = (unsigned short*)alloc((size_t)Mp*HID*2);
  float* gsum   = (float*)alloc(HID*4);
  float* gsq    = (float*)alloc(HID*4);
  float* scale  = (float*)alloc(HID*4);
  float* shift  = (float*)alloc(HID*4);
  int*   bsums  = (int*)  alloc(2*256*4);
  int*   totals = (int*)  alloc(2*4);
  int*   flag   = (int*)  alloc(4);
  unsigned short* fused = h;   // alias: h dead after aggregation

  k_zero<<<256, 256, 0, stream>>>((int*)curD, (int*)curS, gsum, gsq, N);
  k_detect<<<1, 256, 0, stream>>>(ei32, flag);
  k_convert<<<(E+255)/256, 256, 0, stream>>>(ei32, flag, srcI, dstI, curD, curS, E);

  long xn4 = (long)N * KDIM / 4;
  k_cvt_x<<<2048, 256, 0, stream>>>((const float4*)x, (uint2*)xb, xn4);
  k_transcvt<<<(HC*KDIM+255)/256, 256, 0, stream>>>(W_f, Wcat_t, KDIM, HC);
  k_transcvt<<<(HC*KDIM+255)/256, 256, 0, stream>>>(W_b, Wcat_t + (size_t)HC*KDIM, KDIM, HC);
  k_transcvt<<<(HID*KDIM+255)/256, 256, 0, stream>>>(W_fuse, Wfuse_t, KDIM, HID);

  // h[N,512](bf16) = x @ [W_f | W_b]
  k_gemm_mfma<<<dim3(HID/128, Mp/128), 256, 0, stream>>>(xb, Wcat_t, nullptr, h, N, HID, KDIM, nullptr);

  int nodeBlocks = (N + 3) / 4;
  k_att<<<nodeBlocks, 256, 0, stream>>>(h, att_sf, att_df, att_sb, att_db,
                                        asf, adf, asb, adb, N);

  k_scan_local<<<dim3(nb,2), 1024, 0, stream>>>(curD, curS, rsD, curD, rsS, curS, bsums, N, nb);
  k_scan_bsums<<<2, 256, 0, stream>>>(bsums, totals, nb);
  k_scan_add<<<dim3(nb,2), 1024, 0, stream>>>(rsD, curD, rsS, curS, bsums, totals, N, nb);

  k_scatter<<<(E+255)/256, 256, 0, stream>>>(srcI, dstI, curD, curS, listD, listS, E);

  // fused softmax + aggregate, both directions in one dispatch
  k_agg2<<<dim3(nodeBlocks, 2), 256, 0, stream>>>(rsD, listD, rsS, listS,
                                                  asf, adf, asb, adb, h,
                                                  bias_f, bias_b, combined, N);

  // fused(bf16) = combined @ W_fuse + b_fuse  (overwrites dead h)
  k_gemm_mfma<<<dim3(HID/128, Mp/128), 256, 0, stream>>>(combined, Wfuse_t, nullptr, fused, N, HID, KDIM, b_fuse);

  k_bn_stats<<<128, 512, 0, stream>>>(fused, N, gsum, gsq);
  k_bn_final<<<1, 512, 0, stream>>>(gsum, gsq, bn_gamma, bn_beta, scale, shift, N);
  long n4 = (long)N * HID / 4;
  k_bn_apply<<<2048, 256, 0, stream>>>((const uint2*)fused, (const float4*)scale,
                                       (const float4*)shift, (float4*)d_out, n4);

  (void)n_in; (void)out_size; (void)ws_size;
}